// Round 6
// baseline (181.547 us; speedup 1.0000x reference)
//
#include <hip/hip_runtime.h>

// Problem: B=2048, D=2048, N=64 transforms, R=32.
//  out0 (2048x2048 f32) = sum_n gate[b,n] * (x V_n^T U_n^T)
//  out1 (2048x64  f32) = jumprelu(x enc^T - bias)
//  out2 (64 f32)       = ||U_n||_F ||V_n||_F / 256
// Flatten (n,r)->c=2048: two 2048^3 bf16 MFMA GEMMs:
//   Y[b,c]   = x @ Vflat^T          (V already B^T-layout)
//   out[b,d] = (Y .* gate) @ Ut^T   (Ut[d,c] = U[n,d,r] pre-transposed)
// R5->R6 A/B experiment: GEMM2 split-K x2 + f32 atomicAdd (1024 blocks,
// 4/CU, 2x staging MLP; total staging bytes unchanged) vs GEMM1 control
// (512 blocks, 2/CU). Tests latency-bound vs L3-BW-bound staging theory.
// out0 zeroed by 256 extra k_prep blocks (atomics need clean base).

#define D_MODEL 2048
#define BATCH   2048
#define NT      64
#define RANK    32

typedef __attribute__((ext_vector_type(8))) __bf16 bf16x8;
typedef __attribute__((ext_vector_type(4))) float  f32x4;

__device__ __forceinline__ unsigned short f2bf(float f) {
  unsigned int u = __builtin_bit_cast(unsigned int, f);
  u += 0x7FFFu + ((u >> 16) & 1u);          // RNE
  return (unsigned short)(u >> 16);
}

// async global->LDS, 16B per lane. LDS dest is wave-uniform base + lane*16.
__device__ __forceinline__ void gload_lds16(const void* g, void* l) {
  __builtin_amdgcn_global_load_lds(
      (const __attribute__((address_space(1))) unsigned int*)g,
      (__attribute__((address_space(3))) unsigned int*)l,
      16, 0, 0);
}

// ---------------- merged prep ----------------
// blocks [0,1024): x->bf16   [1024,1152): enc->bf16
// blocks [1152,1408): V->bf16 (+sumsq)   [1408,1664): U->Ut bf16 (+sumsq)
// blocks [1664,1920): zero out0 (base for GEMM2 atomics)

__device__ __forceinline__ void block_reduce_store(float ss, float* dst, int slot) {
  __shared__ float red[256];
  int t = threadIdx.x;
  red[t] = ss;
  __syncthreads();
  for (int s = 128; s > 0; s >>= 1) {
    if (t < s) red[t] += red[t + s];
    __syncthreads();
  }
  if (t == 0) dst[slot] = red[0];
}

__global__ void k_prep(const float4* __restrict__ x, const float4* __restrict__ enc,
                       const float4* __restrict__ V, const float4* __restrict__ U,
                       ushort4* __restrict__ xb, ushort4* __restrict__ encb,
                       ushort4* __restrict__ Vb, unsigned short* __restrict__ Ut,
                       float* __restrict__ partV, float* __restrict__ partU,
                       float4* __restrict__ outz) {
  int bid = blockIdx.x, t = threadIdx.x;
  if (bid < 1024) {                      // x: 1048576 float4, 1024 per block
#pragma unroll
    for (int it = 0; it < 4; ++it) {
      int i = bid * 1024 + it * 256 + t;
      float4 v = x[i];
      ushort4 o;
      o.x = f2bf(v.x); o.y = f2bf(v.y); o.z = f2bf(v.z); o.w = f2bf(v.w);
      xb[i] = o;
    }
  } else if (bid < 1152) {               // enc: 32768 float4
    int i = (bid - 1024) * 256 + t;
    float4 v = enc[i];
    ushort4 o;
    o.x = f2bf(v.x); o.y = f2bf(v.y); o.z = f2bf(v.z); o.w = f2bf(v.w);
    encb[i] = o;
  } else if (bid < 1408) {               // V: contiguous convert + sumsq
    int b = bid - 1152;                  // 256 blocks: n=b>>2, quarter=b&3
    size_t base4 = (size_t)b * 4096;
    float ss = 0.f;
    for (int it = 0; it < 16; ++it) {
      size_t idx = base4 + t + it * 256;
      float4 v = V[idx];
      ss += v.x * v.x + v.y * v.y + v.z * v.z + v.w * v.w;
      ushort4 o;
      o.x = f2bf(v.x); o.y = f2bf(v.y); o.z = f2bf(v.z); o.w = f2bf(v.w);
      Vb[idx] = o;
    }
    block_reduce_store(ss, partV, b);
  } else if (bid < 1664) {               // U: transpose-convert + sumsq
    int b = bid - 1408;
    int n = b >> 2;
    size_t base4 = (size_t)b * 4096;
    float ss = 0.f;
    for (int it = 0; it < 16; ++it) {
      size_t idx4 = base4 + t + it * 256;
      float4 v = U[idx4];
      ss += v.x * v.x + v.y * v.y + v.z * v.z + v.w * v.w;
      size_t e = idx4 * 4 - (size_t)n * (D_MODEL * RANK);
      int dcol = (int)(e >> 5);
      int r = (int)(e & 31);
      ushort4 o;
      o.x = f2bf(v.x); o.y = f2bf(v.y); o.z = f2bf(v.z); o.w = f2bf(v.w);
      *(ushort4*)(Ut + (size_t)dcol * 2048 + n * 32 + r) = o;
    }
    block_reduce_store(ss, partU, b);
  } else {                               // zero out0: 1048576 float4 / 256 blocks
    int b = bid - 1664;
    const float4 z4 = {0.f, 0.f, 0.f, 0.f};
#pragma unroll
    for (int it = 0; it < 16; ++it)
      outz[(size_t)b * 4096 + it * 256 + t] = z4;
  }
}

// gate reduce: sum 8 split-K partials, subtract bias, jumprelu. Block 0 also
// finishes the Frobenius norms (partU/partV ready since k_prep completed).
__global__ void k_gate_reduce(const float* __restrict__ part, const float* __restrict__ bias,
                              float* __restrict__ gate,
                              const float* __restrict__ pU, const float* __restrict__ pV,
                              float* __restrict__ frob) {
  int t = threadIdx.x;
  if (blockIdx.x == 0 && t < NT) {
    float su = pU[4 * t] + pU[4 * t + 1] + pU[4 * t + 2] + pU[4 * t + 3];
    float sv = pV[4 * t] + pV[4 * t + 1] + pV[4 * t + 2] + pV[4 * t + 3];
    frob[t] = sqrtf(su) * sqrtf(sv) * (1.0f / 256.0f);
  }
#pragma unroll
  for (int u = 0; u < 4; ++u) {
    int idx = blockIdx.x * 1024 + u * 256 + t;
    float s = 0.f;
#pragma unroll
    for (int z = 0; z < 8; ++z) s += part[(size_t)z * (BATCH * NT) + idx];
    float pre = s - bias[idx & (NT - 1)];
    gate[idx] = pre > 0.f ? pre : 0.f;
  }
}

// ---------------- GEMM (BK=64, XOR-swizzled LDS) ----------------
// A: M x K row-major bf16. Bt: N x K row-major bf16. 256 threads, 4 waves.
// SWZ=1: grid (512,1,Z), XCD-aware decode — lin%8 = XCD owns an 8x8 tile
// region; blockIdx.z gives split-K chunk [z*klen, +klen).
// EPI 0: outB[row*2048+col] = bf16(acc * gate[row*64 + col>>5])
// EPI 1: outF[row*2048+col] = acc
// EPI 3: outF[z*B*NT + row*NT+col] = acc   (split-K partial, N=64)
// EPI 4: atomicAdd(&outF[row*2048+col], acc)  (split-K direct accumulate)
template <int WGM, int WGN, int MI, int NJ, int EPI, int SWZ>
__global__ void gemm_bt(const unsigned short* __restrict__ A,
                        const unsigned short* __restrict__ Bt,
                        const float* __restrict__ aux,
                        unsigned short* __restrict__ outB,
                        float* __restrict__ outF, int K, int klen) {
  constexpr int BM = WGM * MI * 16;
  constexpr int BN = WGN * NJ * 16;
  constexpr int RA = BM / 32;
  constexpr int RB = BN / 32;
  __shared__ __align__(16) unsigned short smem[(BM + BN) * 64];
  unsigned short* As = smem;
  unsigned short* Bs = smem + BM * 64;

  const int tid = threadIdx.x;
  const int w = tid >> 6;
  const int lane = tid & 63;
  const int quad = lane >> 4;
  const int l15 = lane & 15;
  const int wm = w % WGM;
  const int wn = w / WGM;

  int blockM, blockN, kbeg;
  if constexpr (SWZ) {
    // grid.x = 512 = 16 (M/128) x 32 (N/64) tiles; lin%8 -> XCD
    const int lin = blockIdx.x;
    const int xcd = lin & 7;
    const int i = lin >> 3;              // 0..63 within XCD
    blockM = (xcd & 1) * 8 + (i & 7);    // [0,16)
    blockN = (xcd >> 1) * 8 + (i >> 3);  // [0,32)
    kbeg = blockIdx.z * klen;
  } else {
    blockN = blockIdx.x;
    blockM = blockIdx.y;
    kbeg = blockIdx.z * klen;
  }

  // staging: linear LDS slot (row=l>>3, pchunk=l&7) holds logical chunk
  // q = pchunk ^ (row&7)  (XOR swizzle, involutive)
  const int lrow = lane >> 3;
  const int lq = (lane & 7) ^ lrow;
  const unsigned short* Ag = A + (size_t)(blockM * BM + lrow) * K + kbeg + lq * 8;
  const unsigned short* Bg = Bt + (size_t)(blockN * BN + lrow) * K + kbeg + lq * 8;

  // fragment: A[m=l15][k=quad*8+j]; physical chunk = (s*4+quad)^(row&7)
  const int pcs = (quad ^ (lane & 7)) * 16;
  const int rfA = wm * MI * 16 + l15;
  const int rfB = wn * NJ * 16 + l15;

  f32x4 acc[MI][NJ];
  const f32x4 z = {0.f, 0.f, 0.f, 0.f};
#pragma unroll
  for (int i = 0; i < MI; ++i)
#pragma unroll
    for (int j = 0; j < NJ; ++j) acc[i][j] = z;

  for (int k0 = 0; k0 < klen; k0 += 64) {
#pragma unroll
    for (int j = 0; j < RA; ++j)
      gload_lds16(Ag + (size_t)((j * 4 + w) * 8) * K + k0,
                  (char*)As + (j * 4 + w) * 1024);
#pragma unroll
    for (int j = 0; j < RB; ++j)
      gload_lds16(Bg + (size_t)((j * 4 + w) * 8) * K + k0,
                  (char*)Bs + (j * 4 + w) * 1024);
    __syncthreads();
#pragma unroll
    for (int s = 0; s < 2; ++s) {
      bf16x8 af[MI], bfr[NJ];
#pragma unroll
      for (int i = 0; i < MI; ++i)
        af[i] = *(const bf16x8*)((const char*)As + (rfA + i * 16) * 128 + (pcs ^ (s << 6)));
#pragma unroll
      for (int j = 0; j < NJ; ++j)
        bfr[j] = *(const bf16x8*)((const char*)Bs + (rfB + j * 16) * 128 + (pcs ^ (s << 6)));
#pragma unroll
      for (int i = 0; i < MI; ++i)
#pragma unroll
        for (int j = 0; j < NJ; ++j)
          acc[i][j] = __builtin_amdgcn_mfma_f32_16x16x32_bf16(af[i], bfr[j], acc[i][j], 0, 0, 0);
    }
    __syncthreads();
  }

  // epilogue: C/D layout col=lane&15, row=quad*4+reg
  const int row0 = blockM * BM + wm * MI * 16 + quad * 4;
  const int col0 = blockN * BN + wn * NJ * 16 + l15;
#pragma unroll
  for (int i = 0; i < MI; ++i) {
#pragma unroll
    for (int j = 0; j < NJ; ++j) {
      const int col = col0 + j * 16;
#pragma unroll
      for (int t = 0; t < 4; ++t) {
        const int row = row0 + i * 16 + t;
        float v = acc[i][j][t];
        if constexpr (EPI == 0) {
          float g = aux[(size_t)row * NT + (col >> 5)];
          outB[(size_t)row * 2048 + col] = f2bf(v * g);
        } else if constexpr (EPI == 1) {
          outF[(size_t)row * 2048 + col] = v;
        } else if constexpr (EPI == 3) {  // split-K partial, N=64
          outF[(size_t)blockIdx.z * (BATCH * NT) + (size_t)row * NT + col] = v;
        } else {  // EPI 4: split-K direct accumulate
          atomicAdd(&outF[(size_t)row * 2048 + col], v);
        }
      }
    }
  }
}

// ---------------- launch ----------------

extern "C" void kernel_launch(void* const* d_in, const int* in_sizes, int n_in,
                              void* d_out, int out_size, void* d_ws, size_t ws_size,
                              hipStream_t stream) {
  const float* x    = (const float*)d_in[0];
  const float* V    = (const float*)d_in[1];
  const float* U    = (const float*)d_in[2];
  const float* enc  = (const float*)d_in[3];
  const float* bias = (const float*)d_in[4];

  float* out  = (float*)d_out;                        // 2048*2048
  float* gate = out + (size_t)BATCH * D_MODEL;        // 2048*64
  float* frob = gate + (size_t)BATCH * NT;            // 64

  char* ws = (char*)d_ws;                             // ~34 MB used
  unsigned short* xb   = (unsigned short*)(ws);                     // 8 MB
  unsigned short* Vb   = (unsigned short*)(ws + (8u << 20));        // 8 MB
  unsigned short* Ut   = (unsigned short*)(ws + (16u << 20));       // 8 MB
  unsigned short* Yg   = (unsigned short*)(ws + (24u << 20));       // 8 MB
  float* gatePart      = (float*)Yg;                  // 4 MB, dead before GEMM1
  unsigned short* encb = (unsigned short*)(ws + (32u << 20));       // 256 KB
  float* partU = (float*)(ws + (32u << 20) + 262144);
  float* partV = partU + 256;

  // prep: all bf16 conversions + U transpose + Frobenius partials + zero out0
  k_prep<<<1920, 256, 0, stream>>>((const float4*)x, (const float4*)enc,
                                   (const float4*)V, (const float4*)U,
                                   (ushort4*)xb, (ushort4*)encb, (ushort4*)Vb, Ut,
                                   partV, partU, (float4*)out);

  // gate pre-acts, split-K x8: 128 blocks of BM=128 BN=64 klen=256
  gemm_bt<4, 1, 2, 4, 3, 0><<<dim3(1, 16, 8), 256, 0, stream>>>(
      xb, encb, nullptr, nullptr, gatePart, D_MODEL, 256);
  k_gate_reduce<<<128, 256, 0, stream>>>(gatePart, bias, gate, partU, partV, frob);

  // Yg = bf16(gate .* (x @ Vflat^T)): 2048^3, 128x64 tiles, XCD-swizzled
  // (control arm: 512 blocks, 2/CU)
  gemm_bt<2, 2, 4, 2, 0, 1><<<dim3(512, 1, 1), 256, 0, stream>>>(
      xb, Vb, gate, Yg, nullptr, D_MODEL, D_MODEL);

  // out += Yg @ Ut^T: 2048^3, split-K x2, atomic f32 accumulate
  // (experiment arm: 1024 blocks, 4/CU)
  gemm_bt<2, 2, 4, 2, 4, 1><<<dim3(512, 1, 2), 256, 0, stream>>>(
      Yg, Ut, nullptr, nullptr, out, D_MODEL, 1024);
}

// Round 7
// 154.136 us; speedup vs baseline: 1.1778x; 1.1778x over previous
//
#include <hip/hip_runtime.h>

// Problem: B=2048, D=2048, N=64 transforms, R=32.
//  out0 (2048x2048 f32) = sum_n gate[b,n] * (x V_n^T U_n^T)
//  out1 (2048x64  f32) = jumprelu(x enc^T - bias)
//  out2 (64 f32)       = ||U_n||_F ||V_n||_F / 256
// Flatten (n,r)->c=2048: two 2048^3 bf16 MFMA GEMMs:
//   Y[b,c]   = x @ Vflat^T          (V already B^T-layout)
//   out[b,d] = (Y .* gate) @ Ut^T   (Ut[d,c] = U[n,d,r] pre-transposed)
// R6->R7: wave-level split-K x2 (TEAMS=2): 512-thr blocks, two 4-wave
// teams each staging their own K-half; team1 dumps acc to LDS, team0
// adds+stores. 2x in-flight staging per CU, SAME total traffic, NO
// atomics/reduction tax (R6's atomic split-K cost ~8-18us and confounded
// the occupancy test). Discriminates MLP-latency-bound vs ~11TB/s-BW-bound.

#define D_MODEL 2048
#define BATCH   2048
#define NT      64
#define RANK    32

typedef __attribute__((ext_vector_type(8))) __bf16 bf16x8;
typedef __attribute__((ext_vector_type(4))) float  f32x4;

__device__ __forceinline__ unsigned short f2bf(float f) {
  unsigned int u = __builtin_bit_cast(unsigned int, f);
  u += 0x7FFFu + ((u >> 16) & 1u);          // RNE
  return (unsigned short)(u >> 16);
}

// async global->LDS, 16B per lane. LDS dest is wave-uniform base + lane*16.
__device__ __forceinline__ void gload_lds16(const void* g, void* l) {
  __builtin_amdgcn_global_load_lds(
      (const __attribute__((address_space(1))) unsigned int*)g,
      (__attribute__((address_space(3))) unsigned int*)l,
      16, 0, 0);
}

// ---------------- merged prep ----------------
// blocks [0,1024): x->bf16   [1024,1152): enc->bf16
// blocks [1152,1408): V->bf16 (+sumsq)   [1408,1664): U->Ut bf16 (+sumsq)

__device__ __forceinline__ void block_reduce_store(float ss, float* dst, int slot) {
  __shared__ float red[256];
  int t = threadIdx.x;
  red[t] = ss;
  __syncthreads();
  for (int s = 128; s > 0; s >>= 1) {
    if (t < s) red[t] += red[t + s];
    __syncthreads();
  }
  if (t == 0) dst[slot] = red[0];
}

__global__ void k_prep(const float4* __restrict__ x, const float4* __restrict__ enc,
                       const float4* __restrict__ V, const float4* __restrict__ U,
                       ushort4* __restrict__ xb, ushort4* __restrict__ encb,
                       ushort4* __restrict__ Vb, unsigned short* __restrict__ Ut,
                       float* __restrict__ partV, float* __restrict__ partU) {
  int bid = blockIdx.x, t = threadIdx.x;
  if (bid < 1024) {                      // x: 1048576 float4, 1024 per block
#pragma unroll
    for (int it = 0; it < 4; ++it) {
      int i = bid * 1024 + it * 256 + t;
      float4 v = x[i];
      ushort4 o;
      o.x = f2bf(v.x); o.y = f2bf(v.y); o.z = f2bf(v.z); o.w = f2bf(v.w);
      xb[i] = o;
    }
  } else if (bid < 1152) {               // enc: 32768 float4
    int i = (bid - 1024) * 256 + t;
    float4 v = enc[i];
    ushort4 o;
    o.x = f2bf(v.x); o.y = f2bf(v.y); o.z = f2bf(v.z); o.w = f2bf(v.w);
    encb[i] = o;
  } else if (bid < 1408) {               // V: contiguous convert + sumsq
    int b = bid - 1152;                  // 256 blocks: n=b>>2, quarter=b&3
    size_t base4 = (size_t)b * 4096;
    float ss = 0.f;
    for (int it = 0; it < 16; ++it) {
      size_t idx = base4 + t + it * 256;
      float4 v = V[idx];
      ss += v.x * v.x + v.y * v.y + v.z * v.z + v.w * v.w;
      ushort4 o;
      o.x = f2bf(v.x); o.y = f2bf(v.y); o.z = f2bf(v.z); o.w = f2bf(v.w);
      Vb[idx] = o;
    }
    block_reduce_store(ss, partV, b);
  } else {                               // U: transpose-convert + sumsq
    int b = bid - 1408;
    int n = b >> 2;
    size_t base4 = (size_t)b * 4096;
    float ss = 0.f;
    for (int it = 0; it < 16; ++it) {
      size_t idx4 = base4 + t + it * 256;
      float4 v = U[idx4];
      ss += v.x * v.x + v.y * v.y + v.z * v.z + v.w * v.w;
      size_t e = idx4 * 4 - (size_t)n * (D_MODEL * RANK);
      int dcol = (int)(e >> 5);
      int r = (int)(e & 31);
      ushort4 o;
      o.x = f2bf(v.x); o.y = f2bf(v.y); o.z = f2bf(v.z); o.w = f2bf(v.w);
      *(ushort4*)(Ut + (size_t)dcol * 2048 + n * 32 + r) = o;
    }
    block_reduce_store(ss, partU, b);
  }
}

// gate reduce: sum 8 split-K partials, subtract bias, jumprelu. Block 0 also
// finishes the Frobenius norms (partU/partV ready since k_prep completed).
__global__ void k_gate_reduce(const float* __restrict__ part, const float* __restrict__ bias,
                              float* __restrict__ gate,
                              const float* __restrict__ pU, const float* __restrict__ pV,
                              float* __restrict__ frob) {
  int t = threadIdx.x;
  if (blockIdx.x == 0 && t < NT) {
    float su = pU[4 * t] + pU[4 * t + 1] + pU[4 * t + 2] + pU[4 * t + 3];
    float sv = pV[4 * t] + pV[4 * t + 1] + pV[4 * t + 2] + pV[4 * t + 3];
    frob[t] = sqrtf(su) * sqrtf(sv) * (1.0f / 256.0f);
  }
#pragma unroll
  for (int u = 0; u < 4; ++u) {
    int idx = blockIdx.x * 1024 + u * 256 + t;
    float s = 0.f;
#pragma unroll
    for (int z = 0; z < 8; ++z) s += part[(size_t)z * (BATCH * NT) + idx];
    float pre = s - bias[idx & (NT - 1)];
    gate[idx] = pre > 0.f ? pre : 0.f;
  }
}

// ---------------- GEMM (BK=64, XOR-swizzled LDS, optional wave-split-K) ----
// A: M x K row-major bf16. Bt: N x K row-major bf16. TEAMS*256 threads.
// WGM*WGN must be 4 (4 waves per team). Team t covers K-span
// [kbeg + t*klen/TEAMS, +klen/TEAMS) in its own LDS staging buffer; for
// TEAMS=2 team1's accumulators are LDS-reduced into team0 before the store.
// SWZ=1: grid.x=512, lin%8 = XCD owns an 8x8 tile region (L2 locality).
// EPI 0: outB[row*2048+col] = bf16(acc * gate[row*64 + col>>5])
// EPI 1: outF[row*2048+col] = acc
// EPI 3: outF[z*B*NT + row*NT+col] = acc   (grid split-K partial, N=64)
template <int WGM, int WGN, int MI, int NJ, int EPI, int SWZ, int TEAMS>
__global__ __launch_bounds__(TEAMS * 256, 4)
void gemm_bt(const unsigned short* __restrict__ A,
             const unsigned short* __restrict__ Bt,
             const float* __restrict__ aux,
             unsigned short* __restrict__ outB,
             float* __restrict__ outF, int K, int klen) {
  constexpr int BM = WGM * MI * 16;
  constexpr int BN = WGN * NJ * 16;
  constexpr int RA = BM / 32;
  constexpr int RB = BN / 32;
  __shared__ __align__(16) unsigned short smem[TEAMS * (BM + BN) * 64];

  const int tid = threadIdx.x;
  const int w = tid >> 6;
  const int lane = tid & 63;
  const int quad = lane >> 4;
  const int l15 = lane & 15;
  const int team = w >> 2;               // 4 waves per team
  const int wl = w & 3;
  const int wm = wl % WGM;
  const int wn = wl / WGM;

  unsigned short* As = smem + team * (BM + BN) * 64;
  unsigned short* Bs = As + BM * 64;

  int blockM, blockN, kbeg;
  if constexpr (SWZ) {
    // grid.x = 512 = 16 (M/128) x 32 (N/64) tiles; lin%8 -> XCD
    const int lin = blockIdx.x;
    const int xcd = lin & 7;
    const int i = lin >> 3;              // 0..63 within XCD
    blockM = (xcd & 1) * 8 + (i & 7);    // [0,16)
    blockN = (xcd >> 1) * 8 + (i >> 3);  // [0,32)
    kbeg = 0;
  } else {
    blockN = blockIdx.x;
    blockM = blockIdx.y;
    kbeg = blockIdx.z * klen;
  }
  const int kspan = klen / TEAMS;
  kbeg += team * kspan;

  // staging: linear LDS slot (row=l>>3, pchunk=l&7) holds logical chunk
  // q = pchunk ^ (row&7)  (XOR swizzle, involutive)
  const int lrow = lane >> 3;
  const int lq = (lane & 7) ^ lrow;
  const unsigned short* Ag = A + (size_t)(blockM * BM + lrow) * K + kbeg + lq * 8;
  const unsigned short* Bg = Bt + (size_t)(blockN * BN + lrow) * K + kbeg + lq * 8;

  // fragment: A[m=l15][k=quad*8+j]; physical chunk = (s*4+quad)^(row&7)
  const int pcs = (quad ^ (lane & 7)) * 16;
  const int rfA = wm * MI * 16 + l15;
  const int rfB = wn * NJ * 16 + l15;

  f32x4 acc[MI][NJ];
  const f32x4 z = {0.f, 0.f, 0.f, 0.f};
#pragma unroll
  for (int i = 0; i < MI; ++i)
#pragma unroll
    for (int j = 0; j < NJ; ++j) acc[i][j] = z;

  for (int k0 = 0; k0 < kspan; k0 += 64) {
#pragma unroll
    for (int j = 0; j < RA; ++j)
      gload_lds16(Ag + (size_t)((j * 4 + wl) * 8) * K + k0,
                  (char*)As + (j * 4 + wl) * 1024);
#pragma unroll
    for (int j = 0; j < RB; ++j)
      gload_lds16(Bg + (size_t)((j * 4 + wl) * 8) * K + k0,
                  (char*)Bs + (j * 4 + wl) * 1024);
    __syncthreads();
#pragma unroll
    for (int s = 0; s < 2; ++s) {
      bf16x8 af[MI], bfr[NJ];
#pragma unroll
      for (int i = 0; i < MI; ++i)
        af[i] = *(const bf16x8*)((const char*)As + (rfA + i * 16) * 128 + (pcs ^ (s << 6)));
#pragma unroll
      for (int j = 0; j < NJ; ++j)
        bfr[j] = *(const bf16x8*)((const char*)Bs + (rfB + j * 16) * 128 + (pcs ^ (s << 6)));
#pragma unroll
      for (int i = 0; i < MI; ++i)
#pragma unroll
        for (int j = 0; j < NJ; ++j)
          acc[i][j] = __builtin_amdgcn_mfma_f32_16x16x32_bf16(af[i], bfr[j], acc[i][j], 0, 0, 0);
    }
    __syncthreads();
  }

  if constexpr (TEAMS == 2) {
    // team1 -> LDS (reuse staging space; 4*MI*NJ*64 float4 = 32 KB), team0 adds
    float4* red = (float4*)smem;
    if (team == 1) {
#pragma unroll
      for (int i = 0; i < MI; ++i)
#pragma unroll
        for (int j = 0; j < NJ; ++j) {
          float4 v = {acc[i][j][0], acc[i][j][1], acc[i][j][2], acc[i][j][3]};
          red[((wl * MI + i) * NJ + j) * 64 + lane] = v;
        }
    }
    __syncthreads();
    if (team == 1) return;
#pragma unroll
    for (int i = 0; i < MI; ++i)
#pragma unroll
      for (int j = 0; j < NJ; ++j) {
        float4 r = red[((wl * MI + i) * NJ + j) * 64 + lane];
        acc[i][j][0] += r.x; acc[i][j][1] += r.y;
        acc[i][j][2] += r.z; acc[i][j][3] += r.w;
      }
  }

  // epilogue (team0 only when TEAMS==2): C/D layout col=lane&15, row=quad*4+reg
  const int row0 = blockM * BM + wm * MI * 16 + quad * 4;
  const int col0 = blockN * BN + wn * NJ * 16 + l15;
#pragma unroll
  for (int i = 0; i < MI; ++i) {
#pragma unroll
    for (int j = 0; j < NJ; ++j) {
      const int col = col0 + j * 16;
#pragma unroll
      for (int t = 0; t < 4; ++t) {
        const int row = row0 + i * 16 + t;
        float v = acc[i][j][t];
        if constexpr (EPI == 0) {
          float g = aux[(size_t)row * NT + (col >> 5)];
          outB[(size_t)row * 2048 + col] = f2bf(v * g);
        } else if constexpr (EPI == 1) {
          outF[(size_t)row * 2048 + col] = v;
        } else {  // EPI 3: grid split-K partial, N=64
          outF[(size_t)blockIdx.z * (BATCH * NT) + (size_t)row * NT + col] = v;
        }
      }
    }
  }
}

// ---------------- launch ----------------

extern "C" void kernel_launch(void* const* d_in, const int* in_sizes, int n_in,
                              void* d_out, int out_size, void* d_ws, size_t ws_size,
                              hipStream_t stream) {
  const float* x    = (const float*)d_in[0];
  const float* V    = (const float*)d_in[1];
  const float* U    = (const float*)d_in[2];
  const float* enc  = (const float*)d_in[3];
  const float* bias = (const float*)d_in[4];

  float* out  = (float*)d_out;                        // 2048*2048
  float* gate = out + (size_t)BATCH * D_MODEL;        // 2048*64
  float* frob = gate + (size_t)BATCH * NT;            // 64

  char* ws = (char*)d_ws;                             // ~34 MB used
  unsigned short* xb   = (unsigned short*)(ws);                     // 8 MB
  unsigned short* Vb   = (unsigned short*)(ws + (8u << 20));        // 8 MB
  unsigned short* Ut   = (unsigned short*)(ws + (16u << 20));       // 8 MB
  unsigned short* Yg   = (unsigned short*)(ws + (24u << 20));       // 8 MB
  float* gatePart      = (float*)Yg;                  // 4 MB, dead before GEMM1
  unsigned short* encb = (unsigned short*)(ws + (32u << 20));       // 256 KB
  float* partU = (float*)(ws + (32u << 20) + 262144);
  float* partV = partU + 256;

  // prep: all bf16 conversions + U transpose + Frobenius partials
  k_prep<<<1664, 256, 0, stream>>>((const float4*)x, (const float4*)enc,
                                   (const float4*)V, (const float4*)U,
                                   (ushort4*)xb, (ushort4*)encb, (ushort4*)Vb, Ut,
                                   partV, partU);

  // gate pre-acts, grid split-K x8: 128 blocks of BM=128 BN=64 klen=256
  gemm_bt<4, 1, 2, 4, 3, 0, 1><<<dim3(1, 16, 8), 256, 0, stream>>>(
      xb, encb, nullptr, nullptr, gatePart, D_MODEL, 256);
  k_gate_reduce<<<128, 256, 0, stream>>>(gatePart, bias, gate, partU, partV, frob);

  // Yg = bf16(gate .* (x @ Vflat^T)): 2048^3, 128x64 tiles, XCD-swizzled,
  // wave-split-K x2 (512 blocks x 512 thr = 2 blocks/CU, 16 waves/CU)
  gemm_bt<2, 2, 4, 2, 0, 1, 2><<<dim3(512, 1, 1), 512, 0, stream>>>(
      xb, Vb, gate, Yg, nullptr, D_MODEL, D_MODEL);

  // out = Yg @ Ut^T: 2048^3, fp32 store, XCD-swizzled, wave-split-K x2
  gemm_bt<2, 2, 4, 2, 1, 1, 2><<<dim3(512, 1, 1), 512, 0, stream>>>(
      Yg, Ut, nullptr, nullptr, out, D_MODEL, D_MODEL);
}